// Round 11
// baseline (108.021 us; speedup 1.0000x reference)
//
#include <hip/hip_runtime.h>
#include <stdint.h>

#define NB 64
#define NN 1024
#define CDIM 512
#define KK 64

typedef __attribute__((ext_vector_type(4))) float f32x4;
typedef __attribute__((ext_vector_type(8))) short short8;

__device__ __forceinline__ unsigned short f2bf(float f) {
  unsigned int u = __float_as_uint(f);
  return (unsigned short)((u + 0x7fffu + ((u >> 16) & 1u)) >> 16);
}
__device__ __forceinline__ float bf2f(unsigned short h) {
  return __uint_as_float(((unsigned int)h) << 16);
}

__device__ __forceinline__ void lgkm_barrier() {
  // raw workgroup barrier that does NOT drain vmcnt (k2 only)
  asm volatile("s_waitcnt lgkmcnt(0)" ::: "memory");
  __builtin_amdgcn_sched_barrier(0);
  __builtin_amdgcn_s_barrier();
}

// ---------------- K0: centers fp32 -> bf16 ----------------
__global__ __launch_bounds__(256) void k0_cvt(const float* __restrict__ cc,
                                              unsigned short* __restrict__ ccb) {
  int i = blockIdx.x * 256 + threadIdx.x;   // grid sized exactly KK*CDIM/256
  ccb[i] = f2bf(cc[i]);
}

// ---- K1: logits + softmax + a^T + xT — c-split wave pairs, 8 waves/CU ----
// grid: (8, 64 b) = 512 blocks, 256 thr = 4 waves = 2 pairs x 2 c-halves.
// Pair p = w>>1 owns n-chunk nc = bx*2+p (64 n); wave ch = w&1 owns c-half
// [ch*256, ch*256+256): 8 steps of {frag loads, 4x4 MFMA partial logits,
// lane-pair transpose -> private slab, contiguous xT drain}. Then ONE
// syncthreads: exchange partial accs via LDS; softmax duty split (ch=0: tn0,1;
// ch=1: tn2,3); a-pack into pair slab; sync; cooperative a_t drain.
// Layouts (chunk-contiguous, identical to r10):
//   xT[b][nc][c=512][n2=32 u32], a_t[b][nc][k=64][n2=32 u32]
__global__ __launch_bounds__(256, 2) void k1_assign(const float* __restrict__ x,
    const unsigned short* __restrict__ ccb, unsigned int* __restrict__ a_t32,
    unsigned int* __restrict__ xT32) {
  const int b = blockIdx.y;
  const int tid = threadIdx.x;
  const int w = tid >> 6;
  const int l = tid & 63;
  const int lr = l & 15;
  const int lg = l >> 4;
  const int pair = w >> 1;
  const int ch = w & 1;
  const int nc = (blockIdx.x << 1) + pair;
  const int n0 = nc << 6;
  const int cbase = ch << 8;
  const int codd = l & 1;

  __shared__ unsigned int xsw_all[4][32 * 33];   // per-wave transpose slabs
  __shared__ unsigned int asw_all[2][64 * 33];   // per-pair a slabs
  __shared__ f32x4 pacc[2][2][2][4][64];         // [pair][writer_ch][tn_loc][tk][lane]

  unsigned int* xsw = xsw_all[w];
  unsigned int* asw = asw_all[pair];

  const float* xr = x + ((size_t)b * NN + n0 + lr) * CDIM + cbase + (lg << 3);
  const unsigned short* cb = ccb + lr * CDIM + cbase + (lg << 3);
  const size_t xTbase = ((size_t)((b << 4) + nc)) << 14;  // *512*32 u32

  f32x4 acc[4][4];
  #pragma unroll
  for (int i = 0; i < 4; ++i)
    #pragma unroll
    for (int j = 0; j < 4; ++j) acc[i][j] = (f32x4){0.f, 0.f, 0.f, 0.f};

  #pragma unroll 2
  for (int step = 0; step < 8; ++step) {
    const int cs = step << 5;           // within the wave's 256-c half
    short8 af[4];
    #pragma unroll
    for (int tn = 0; tn < 4; ++tn) {
      f32x4 xa = *(const f32x4*)(xr + (size_t)(tn << 4) * CDIM + cs);
      f32x4 xb = *(const f32x4*)(xr + (size_t)(tn << 4) * CDIM + cs + 4);
      short8 t;
      t[0] = (short)f2bf(xa[0]); t[1] = (short)f2bf(xa[1]);
      t[2] = (short)f2bf(xa[2]); t[3] = (short)f2bf(xa[3]);
      t[4] = (short)f2bf(xb[0]); t[5] = (short)f2bf(xb[1]);
      t[6] = (short)f2bf(xb[2]); t[7] = (short)f2bf(xb[3]);
      af[tn] = t;
    }
    short8 bq0 = *(const short8*)(cb + cs);
    short8 bq1 = *(const short8*)(cb + 16 * CDIM + cs);
    short8 bq2 = *(const short8*)(cb + 32 * CDIM + cs);
    short8 bq3 = *(const short8*)(cb + 48 * CDIM + cs);
    #pragma unroll
    for (int tn = 0; tn < 4; ++tn) {
      acc[tn][0] = __builtin_amdgcn_mfma_f32_16x16x32_bf16(af[tn], bq0, acc[tn][0], 0, 0, 0);
      acc[tn][1] = __builtin_amdgcn_mfma_f32_16x16x32_bf16(af[tn], bq1, acc[tn][1], 0, 0, 0);
      acc[tn][2] = __builtin_amdgcn_mfma_f32_16x16x32_bf16(af[tn], bq2, acc[tn][2], 0, 0, 0);
      acc[tn][3] = __builtin_amdgcn_mfma_f32_16x16x32_bf16(af[tn], bq3, acc[tn][3], 0, 0, 0);
    }
    // lane-pair transpose af -> private slab (rows = c within step, cols = n-pair)
    #pragma unroll
    for (int tn = 0; tn < 4; ++tn) {
      #pragma unroll
      for (int q = 0; q < 4; ++q) {
        unsigned int own = ((const unsigned int*)&af[tn])[q];
        unsigned int oth = (unsigned int)__shfl_xor((int)own, 1);
        unsigned int v = codd ? ((oth >> 16) | (own & 0xffff0000u))
                              : ((own & 0xffffu) | (oth << 16));
        xsw[((lg << 3) + (q << 1) + codd) * 33 + (tn << 3) + (lr >> 1)] = v;
      }
    }
    // wave-synchronous contiguous drain: 2 c-rows x 128 B per instr
    #pragma unroll
    for (int i = 0; i < 16; ++i) {
      const int row = (i << 1) + (l >> 5);
      xT32[xTbase + ((size_t)(cbase + cs + row) << 5) + (l & 31)] =
          xsw[row * 33 + (l & 31)];
    }
  }

  // ---- exchange partial logits: write NON-duty accs, sync, add partner's ----
  // duty: ch=0 -> tn {0,1}; ch=1 -> tn {2,3}. Writer stores its non-duty accs.
  {
    const int nd0 = ch ? 0 : 2;   // first non-duty tn
    #pragma unroll
    for (int t2 = 0; t2 < 2; ++t2)
      #pragma unroll
      for (int tk = 0; tk < 4; ++tk)
        pacc[pair][ch][t2][tk][l] = acc[nd0 + t2][tk];
  }
  __syncthreads();
  {
    const int d0 = ch ? 2 : 0;    // first duty tn
    #pragma unroll
    for (int t2 = 0; t2 < 2; ++t2)
      #pragma unroll
      for (int tk = 0; tk < 4; ++tk) {
        f32x4 o = pacc[pair][1 - ch][t2][tk][l];
        acc[d0 + t2][0 + tk] += 0;  // keep indexing simple below
        acc[d0 + t2][tk][0] += o[0];
        acc[d0 + t2][tk][1] += o[1];
        acc[d0 + t2][tk][2] += o[2];
        acc[d0 + t2][tk][3] += o[3];
      }
  }

  // ---- softmax on duty tiles; pack a^T into pair slab ----
  {
    const int d0 = ch ? 2 : 0;
    #pragma unroll
    for (int t2 = 0; t2 < 2; ++t2) {
      const int tn = d0 + t2;
      #pragma unroll
      for (int j = 0; j < 4; ++j) {
        float m = fmaxf(fmaxf(acc[tn][0][j], acc[tn][1][j]),
                        fmaxf(acc[tn][2][j], acc[tn][3][j]));
        m = fmaxf(m, __shfl_xor(m, 1));
        m = fmaxf(m, __shfl_xor(m, 2));
        m = fmaxf(m, __shfl_xor(m, 4));
        m = fmaxf(m, __shfl_xor(m, 8));
        float e0 = __expf(acc[tn][0][j] - m);
        float e1 = __expf(acc[tn][1][j] - m);
        float e2 = __expf(acc[tn][2][j] - m);
        float e3 = __expf(acc[tn][3][j] - m);
        float s = e0 + e1 + e2 + e3;
        s += __shfl_xor(s, 1); s += __shfl_xor(s, 2);
        s += __shfl_xor(s, 4); s += __shfl_xor(s, 8);
        float inv = 1.0f / s;
        acc[tn][0][j] = e0 * inv;
        acc[tn][1][j] = e1 * inv;
        acc[tn][2][j] = e2 * inv;
        acc[tn][3][j] = e3 * inv;
      }
      // a^T pack: n-pair (2jp, 2jp+1) same-lane; col = tn*8 + lg*2 + jp
      #pragma unroll
      for (int tk = 0; tk < 4; ++tk)
        #pragma unroll
        for (int jp = 0; jp < 2; ++jp) {
          unsigned int v = (unsigned int)f2bf(acc[tn][tk][2 * jp]) |
                           ((unsigned int)f2bf(acc[tn][tk][2 * jp + 1]) << 16);
          asw[((tk << 4) + lr) * 33 + (tn << 3) + (lg << 1) + jp] = v;
        }
    }
  }
  __syncthreads();

  // ---- cooperative a_t drain: both pairs, 16 u32/thread, coalesced ----
  {
    const size_t atb0 = ((size_t)((b << 4) + (blockIdx.x << 1))) << 11;
    #pragma unroll
    for (int i = 0; i < 16; ++i) {
      const int f = (i << 8) + tid;       // 0..4095
      const int p = f >> 11;              // pair
      const int k = (f >> 5) & 63;
      const int col = f & 31;
      a_t32[atb0 + (((size_t)p) << 11) + (k << 5) + col] =
          asw_all[p][k * 33 + col];
    }
  }
}

// ---- K2: agg = a^T x via MFMA; chunked inputs; a_sum computed in-kernel ----
// grid: (8 c-slices, 64 b) = 512 blocks, 256 thr = 4 waves (k-split 16 each).
// Per chunk it: stage xT[b][it][c0..c0+64)][64n] (8 KB CONTIGUOUS) via 8 u32
// loads/thread into stride-38 LDS (dbuf); A-frags direct from a_t[b][it][k][n].
// T14 prefetch; raw lgkm-only barriers keep prefetched loads in flight.
#define XRS 38
__global__ __launch_bounds__(256) void k2_agg(
    const unsigned short* __restrict__ a_t, const unsigned int* __restrict__ xT32,
    const float* __restrict__ cc, float* __restrict__ out,
    float* __restrict__ sumsq) {
  const int b = blockIdx.y;
  const int c0 = blockIdx.x << 6;
  const int tid = threadIdx.x;
  const int w = tid >> 6;
  const int l = tid & 63;
  const int lr = l & 15;
  const int lg = l >> 4;

  __shared__ unsigned int xs[2][64 * XRS];  // 9728 B each
  __shared__ float red[4];

  f32x4 acc[4];
  #pragma unroll
  for (int i = 0; i < 4; ++i) acc[i] = (f32x4){0.f, 0.f, 0.f, 0.f};
  float ssum = 0.f;   // per-lane partial of a_sum[k=16w+lr]

  // A-frag pointer: chunk-stride 4096 ush; row k=16w+lr (64 ush), off lg*8
  const unsigned short* ap =
      a_t + (((size_t)(b << 4)) << 12) + (((w << 4) + lr) << 6) + (lg << 3);
  // xT stage pointer: chunk-stride 16384 u32; c-row c0 + tid>>5, col tid&31
  const unsigned int* xg =
      xT32 + (((size_t)(b << 4)) << 14) + ((c0 + (tid >> 5)) << 5) + (tid & 31);

  // ---- prologue: stage chunk 0, load chunk-0 A-frags ----
  #pragma unroll
  for (int p = 0; p < 8; ++p) {
    const int f = (p << 8) + tid;
    xs[0][(f >> 5) * XRS + (f & 31)] = xg[p << 8];
  }
  short8 a_cur0 = *(const short8*)(ap);
  short8 a_cur1 = *(const short8*)(ap + 32);
  lgkm_barrier();

  for (int it = 0; it < 16; ++it) {
    const int cur = it & 1;
    unsigned int xr[8];
    short8 a_nxt0, a_nxt1;
    if (it < 15) {
      const size_t cho = ((size_t)(it + 1)) << 14;      // u32 chunk offset
      const size_t cha = ((size_t)(it + 1)) << 12;      // ush chunk offset
      #pragma unroll
      for (int p = 0; p < 8; ++p) xr[p] = xg[cho + (p << 8)];
      a_nxt0 = *(const short8*)(ap + cha);
      a_nxt1 = *(const short8*)(ap + cha + 32);
    }
    #pragma unroll
    for (int i = 0; i < 8; ++i)
      ssum += bf2f((unsigned short)a_cur0[i]) + bf2f((unsigned short)a_cur1[i]);
    #pragma unroll
    for (int ns = 0; ns < 64; ns += 32) {
      const short8 af = ns == 0 ? a_cur0 : a_cur1;
      #pragma unroll
      for (int ct = 0; ct < 4; ++ct) {
        const int row = (ct << 4) + lr;
        const unsigned long long* bp = (const unsigned long long*)
            &xs[cur][row * XRS + (ns >> 1) + (lg << 2)];
        union { unsigned long long q[2]; short8 s; } u;
        u.q[0] = bp[0];
        u.q[1] = bp[1];
        acc[ct] = __builtin_amdgcn_mfma_f32_16x16x32_bf16(af, u.s, acc[ct], 0, 0, 0);
      }
    }
    if (it < 15) {
      #pragma unroll
      for (int p = 0; p < 8; ++p) {
        const int f = (p << 8) + tid;
        xs[cur ^ 1][(f >> 5) * XRS + (f & 31)] = xr[p];
      }
      a_cur0 = a_nxt0;
      a_cur1 = a_nxt1;
    }
    lgkm_barrier();
  }

  // a_sum reduce over lg groups; lane lr holds a_sum for k=16w+lr
  ssum += __shfl_xor(ssum, 16);
  ssum += __shfl_xor(ssum, 32);

  float lsum = 0.f;
  #pragma unroll
  for (int j = 0; j < 4; ++j) {
    const float asum_e = __shfl(ssum, (lg << 2) + j);   // a_sum[k=16w+lg*4+j]
    #pragma unroll
    for (int ct = 0; ct < 4; ++ct) {
      int k = (w << 4) + (lg << 2) + j;
      int c = c0 + (ct << 4) + lr;
      float v = acc[ct][j] - asum_e * cc[k * CDIM + c];
      out[((size_t)b << 15) + (k << 9) + c] = v;
      lsum += v * v;
    }
  }
  lsum += __shfl_xor(lsum, 1);  lsum += __shfl_xor(lsum, 2);
  lsum += __shfl_xor(lsum, 4);  lsum += __shfl_xor(lsum, 8);
  lsum += __shfl_xor(lsum, 16); lsum += __shfl_xor(lsum, 32);
  if (l == 0) red[w] = lsum;
  __syncthreads();
  if (tid == 0) atomicAdd(&sumsq[b], red[0] + red[1] + red[2] + red[3]);
}

// ---------------- K3: l2 normalize per batch ----------------
__global__ __launch_bounds__(256) void k3_norm(float* __restrict__ out,
                                               const float* __restrict__ sumsq) {
  int idx = blockIdx.x * 256 + threadIdx.x;   // grid exact: 2048*256 = 2M/4
  int b = idx >> 13;                          // 8192 float4 per batch
  float s = sumsq[b];
  float scale = 1.0f / sqrtf(fmaxf(s, 1e-12f));
  f32x4* io = (f32x4*)out;
  f32x4 v = io[idx];
  v[0] *= scale; v[1] *= scale; v[2] *= scale; v[3] *= scale;
  io[idx] = v;
}

extern "C" void kernel_launch(void* const* d_in, const int* in_sizes, int n_in,
                              void* d_out, int out_size, void* d_ws, size_t ws_size,
                              hipStream_t stream) {
  const float* x  = (const float*)d_in[0];
  const float* cc = (const float*)d_in[1];
  float* out = (float*)d_out;
  char* ws = (char*)d_ws;
  // ws: [a_t bf16 8MiB][ccb 64KiB][sumsq 256B] ... [xT 64MiB @16MiB]
  unsigned short* a_t = (unsigned short*)ws;
  unsigned int* a_t32 = (unsigned int*)ws;
  unsigned short* ccb = (unsigned short*)(ws + (8u << 20));
  float* sumsq = (float*)(ws + (8u << 20) + (64u << 10));
  unsigned int* xT32 = (unsigned int*)(ws + (16u << 20));

  (void)hipMemsetAsync(sumsq, 0, NB * 4, stream);
  k0_cvt<<<dim3((KK * CDIM) / 256), 256, 0, stream>>>(cc, ccb);
  k1_assign<<<dim3(8, NB), 256, 0, stream>>>(x, ccb, a_t32, xT32);
  k2_agg<<<dim3(8, NB), 256, 0, stream>>>(a_t, xT32, cc, out, sumsq);
  k3_norm<<<dim3(2048), 256, 0, stream>>>(out, sumsq);
}

// Round 12
// 73.760 us; speedup vs baseline: 1.4645x; 1.4645x over previous
//
#include <hip/hip_runtime.h>
#include <stdint.h>

#define NB 64
#define NN 1024
#define CDIM 512
#define KK 64

typedef __attribute__((ext_vector_type(4))) float f32x4;
typedef __attribute__((ext_vector_type(8))) short short8;

__device__ __forceinline__ unsigned short f2bf(float f) {
  unsigned int u = __float_as_uint(f);
  return (unsigned short)((u + 0x7fffu + ((u >> 16) & 1u)) >> 16);
}
__device__ __forceinline__ float bf2f(unsigned short h) {
  return __uint_as_float(((unsigned int)h) << 16);
}

__device__ __forceinline__ void lgkm_barrier() {
  // raw workgroup barrier that does NOT drain vmcnt (k2 only)
  asm volatile("s_waitcnt lgkmcnt(0)" ::: "memory");
  __builtin_amdgcn_sched_barrier(0);
  __builtin_amdgcn_s_barrier();
}

// ---------------- K0: centers fp32 -> bf16 ----------------
__global__ __launch_bounds__(256) void k0_cvt(const float* __restrict__ cc,
                                              unsigned short* __restrict__ ccb) {
  int i = blockIdx.x * 256 + threadIdx.x;   // grid sized exactly KK*CDIM/256
  ccb[i] = f2bf(cc[i]);
}

// ---- K1: logits + softmax + a^T + xT — c-split wave pairs, STATIC reg indexing ----
// grid: (8, 64 b) = 512 blocks, 256 thr = 4 waves = 2 pairs x 2 c-halves
// -> 2 blocks/CU = 8 waves/CU (2/SIMD) for latency hiding.
// Pair p = w>>1 owns n-chunk nc = bx*2+p; wave ch = w&1 owns c-half ch*256..+256.
// ALL acc[] indices are compile-time literals (rule #20): duty split is a
// wave-uniform if(ch==0)/else with macro-expanded bodies.
#define SM_AND_PACK(TN)                                                        \
  do {                                                                         \
    _Pragma("unroll")                                                          \
    for (int j = 0; j < 4; ++j) {                                              \
      float m = fmaxf(fmaxf(acc[TN][0][j], acc[TN][1][j]),                     \
                      fmaxf(acc[TN][2][j], acc[TN][3][j]));                    \
      m = fmaxf(m, __shfl_xor(m, 1));                                          \
      m = fmaxf(m, __shfl_xor(m, 2));                                          \
      m = fmaxf(m, __shfl_xor(m, 4));                                          \
      m = fmaxf(m, __shfl_xor(m, 8));                                          \
      float e0 = __expf(acc[TN][0][j] - m);                                    \
      float e1 = __expf(acc[TN][1][j] - m);                                    \
      float e2 = __expf(acc[TN][2][j] - m);                                    \
      float e3 = __expf(acc[TN][3][j] - m);                                    \
      float s = e0 + e1 + e2 + e3;                                             \
      s += __shfl_xor(s, 1); s += __shfl_xor(s, 2);                            \
      s += __shfl_xor(s, 4); s += __shfl_xor(s, 8);                            \
      float inv = 1.0f / s;                                                    \
      acc[TN][0][j] = e0 * inv;                                                \
      acc[TN][1][j] = e1 * inv;                                                \
      acc[TN][2][j] = e2 * inv;                                                \
      acc[TN][3][j] = e3 * inv;                                                \
    }                                                                          \
    _Pragma("unroll")                                                          \
    for (int tk = 0; tk < 4; ++tk) {                                           \
      _Pragma("unroll")                                                        \
      for (int jp = 0; jp < 2; ++jp) {                                         \
        unsigned int v = (unsigned int)f2bf(acc[TN][tk][2 * jp]) |             \
                         ((unsigned int)f2bf(acc[TN][tk][2 * jp + 1]) << 16);  \
        asw[((tk << 4) + lr) * 33 + ((TN) << 3) + (lg << 1) + jp] = v;         \
      }                                                                        \
    }                                                                          \
  } while (0)

__global__ __launch_bounds__(256, 2) void k1_assign(const float* __restrict__ x,
    const unsigned short* __restrict__ ccb, unsigned int* __restrict__ a_t32,
    unsigned int* __restrict__ xT32) {
  const int b = blockIdx.y;
  const int tid = threadIdx.x;
  const int w = tid >> 6;
  const int l = tid & 63;
  const int lr = l & 15;
  const int lg = l >> 4;
  const int pair = w >> 1;
  const int ch = w & 1;
  const int nc = (blockIdx.x << 1) + pair;
  const int n0 = nc << 6;
  const int cbase = ch << 8;
  const int codd = l & 1;

  __shared__ unsigned int xsw_all[4][32 * 33];   // per-wave transpose slabs
  __shared__ unsigned int asw_all[2][64 * 33];   // per-pair a slabs
  __shared__ f32x4 pacc[2][2][2][4][64];         // [pair][writer_ch][t2][tk][lane]

  unsigned int* xsw = xsw_all[w];
  unsigned int* asw = asw_all[pair];

  const float* xr = x + ((size_t)b * NN + n0 + lr) * CDIM + cbase + (lg << 3);
  const unsigned short* cb = ccb + lr * CDIM + cbase + (lg << 3);
  const size_t xTbase = ((size_t)((b << 4) + nc)) << 14;  // *512*32 u32

  f32x4 acc[4][4];
  #pragma unroll
  for (int i = 0; i < 4; ++i)
    #pragma unroll
    for (int j = 0; j < 4; ++j) acc[i][j] = (f32x4){0.f, 0.f, 0.f, 0.f};

  #pragma unroll 2
  for (int step = 0; step < 8; ++step) {
    const int cs = step << 5;           // within the wave's 256-c half
    short8 af[4];
    #pragma unroll
    for (int tn = 0; tn < 4; ++tn) {
      f32x4 xa = *(const f32x4*)(xr + (size_t)(tn << 4) * CDIM + cs);
      f32x4 xb = *(const f32x4*)(xr + (size_t)(tn << 4) * CDIM + cs + 4);
      short8 t;
      t[0] = (short)f2bf(xa[0]); t[1] = (short)f2bf(xa[1]);
      t[2] = (short)f2bf(xa[2]); t[3] = (short)f2bf(xa[3]);
      t[4] = (short)f2bf(xb[0]); t[5] = (short)f2bf(xb[1]);
      t[6] = (short)f2bf(xb[2]); t[7] = (short)f2bf(xb[3]);
      af[tn] = t;
    }
    short8 bq0 = *(const short8*)(cb + cs);
    short8 bq1 = *(const short8*)(cb + 16 * CDIM + cs);
    short8 bq2 = *(const short8*)(cb + 32 * CDIM + cs);
    short8 bq3 = *(const short8*)(cb + 48 * CDIM + cs);
    #pragma unroll
    for (int tn = 0; tn < 4; ++tn) {
      acc[tn][0] = __builtin_amdgcn_mfma_f32_16x16x32_bf16(af[tn], bq0, acc[tn][0], 0, 0, 0);
      acc[tn][1] = __builtin_amdgcn_mfma_f32_16x16x32_bf16(af[tn], bq1, acc[tn][1], 0, 0, 0);
      acc[tn][2] = __builtin_amdgcn_mfma_f32_16x16x32_bf16(af[tn], bq2, acc[tn][2], 0, 0, 0);
      acc[tn][3] = __builtin_amdgcn_mfma_f32_16x16x32_bf16(af[tn], bq3, acc[tn][3], 0, 0, 0);
    }
    // lane-pair transpose af -> private slab (rows = c within step, cols = n-pair)
    #pragma unroll
    for (int tn = 0; tn < 4; ++tn) {
      #pragma unroll
      for (int q = 0; q < 4; ++q) {
        unsigned int own = ((const unsigned int*)&af[tn])[q];
        unsigned int oth = (unsigned int)__shfl_xor((int)own, 1);
        unsigned int v = codd ? ((oth >> 16) | (own & 0xffff0000u))
                              : ((own & 0xffffu) | (oth << 16));
        xsw[((lg << 3) + (q << 1) + codd) * 33 + (tn << 3) + (lr >> 1)] = v;
      }
    }
    // wave-synchronous contiguous drain: 2 c-rows x 128 B per instr
    #pragma unroll
    for (int i = 0; i < 16; ++i) {
      const int row = (i << 1) + (l >> 5);
      xT32[xTbase + ((size_t)(cbase + cs + row) << 5) + (l & 31)] =
          xsw[row * 33 + (l & 31)];
    }
  }

  // ---- exchange partial logits (STATIC indices, wave-uniform branch) ----
  if (ch == 0) {
    #pragma unroll
    for (int tk = 0; tk < 4; ++tk) {
      pacc[pair][0][0][tk][l] = acc[2][tk];
      pacc[pair][0][1][tk][l] = acc[3][tk];
    }
  } else {
    #pragma unroll
    for (int tk = 0; tk < 4; ++tk) {
      pacc[pair][1][0][tk][l] = acc[0][tk];
      pacc[pair][1][1][tk][l] = acc[1][tk];
    }
  }
  __syncthreads();
  if (ch == 0) {
    #pragma unroll
    for (int tk = 0; tk < 4; ++tk) {
      f32x4 o0 = pacc[pair][1][0][tk][l];
      f32x4 o1 = pacc[pair][1][1][tk][l];
      acc[0][tk][0] += o0[0]; acc[0][tk][1] += o0[1];
      acc[0][tk][2] += o0[2]; acc[0][tk][3] += o0[3];
      acc[1][tk][0] += o1[0]; acc[1][tk][1] += o1[1];
      acc[1][tk][2] += o1[2]; acc[1][tk][3] += o1[3];
    }
    SM_AND_PACK(0);
    SM_AND_PACK(1);
  } else {
    #pragma unroll
    for (int tk = 0; tk < 4; ++tk) {
      f32x4 o0 = pacc[pair][0][0][tk][l];
      f32x4 o1 = pacc[pair][0][1][tk][l];
      acc[2][tk][0] += o0[0]; acc[2][tk][1] += o0[1];
      acc[2][tk][2] += o0[2]; acc[2][tk][3] += o0[3];
      acc[3][tk][0] += o1[0]; acc[3][tk][1] += o1[1];
      acc[3][tk][2] += o1[2]; acc[3][tk][3] += o1[3];
    }
    SM_AND_PACK(2);
    SM_AND_PACK(3);
  }
  __syncthreads();

  // ---- cooperative a_t drain: both pairs, 16 u32/thread, coalesced ----
  {
    const size_t atb0 = ((size_t)((b << 4) + (blockIdx.x << 1))) << 11;
    #pragma unroll
    for (int i = 0; i < 16; ++i) {
      const int f = (i << 8) + tid;       // 0..4095
      const int p = f >> 11;              // pair
      const int k = (f >> 5) & 63;
      const int col = f & 31;
      a_t32[atb0 + (((size_t)p) << 11) + (k << 5) + col] =
          asw_all[p][k * 33 + col];
    }
  }
}

// ---- K2: agg = a^T x via MFMA; chunked inputs; a_sum computed in-kernel ----
// grid: (8 c-slices, 64 b) = 512 blocks, 256 thr = 4 waves (k-split 16 each).
// Per chunk it: stage xT[b][it][c0..c0+64)][64n] (8 KB CONTIGUOUS) via 8 u32
// loads/thread into stride-38 LDS (dbuf); A-frags direct from a_t[b][it][k][n].
// T14 prefetch; raw lgkm-only barriers keep prefetched loads in flight.
#define XRS 38
__global__ __launch_bounds__(256) void k2_agg(
    const unsigned short* __restrict__ a_t, const unsigned int* __restrict__ xT32,
    const float* __restrict__ cc, float* __restrict__ out,
    float* __restrict__ sumsq) {
  const int b = blockIdx.y;
  const int c0 = blockIdx.x << 6;
  const int tid = threadIdx.x;
  const int w = tid >> 6;
  const int l = tid & 63;
  const int lr = l & 15;
  const int lg = l >> 4;

  __shared__ unsigned int xs[2][64 * XRS];  // 9728 B each
  __shared__ float red[4];

  f32x4 acc[4];
  #pragma unroll
  for (int i = 0; i < 4; ++i) acc[i] = (f32x4){0.f, 0.f, 0.f, 0.f};
  float ssum = 0.f;   // per-lane partial of a_sum[k=16w+lr]

  // A-frag pointer: chunk-stride 4096 ush; row k=16w+lr (64 ush), off lg*8
  const unsigned short* ap =
      a_t + (((size_t)(b << 4)) << 12) + (((w << 4) + lr) << 6) + (lg << 3);
  // xT stage pointer: chunk-stride 16384 u32; c-row c0 + tid>>5, col tid&31
  const unsigned int* xg =
      xT32 + (((size_t)(b << 4)) << 14) + ((c0 + (tid >> 5)) << 5) + (tid & 31);

  // ---- prologue: stage chunk 0, load chunk-0 A-frags ----
  #pragma unroll
  for (int p = 0; p < 8; ++p) {
    const int f = (p << 8) + tid;
    xs[0][(f >> 5) * XRS + (f & 31)] = xg[p << 8];
  }
  short8 a_cur0 = *(const short8*)(ap);
  short8 a_cur1 = *(const short8*)(ap + 32);
  lgkm_barrier();

  for (int it = 0; it < 16; ++it) {
    const int cur = it & 1;
    unsigned int xr[8];
    short8 a_nxt0, a_nxt1;
    if (it < 15) {
      const size_t cho = ((size_t)(it + 1)) << 14;      // u32 chunk offset
      const size_t cha = ((size_t)(it + 1)) << 12;      // ush chunk offset
      #pragma unroll
      for (int p = 0; p < 8; ++p) xr[p] = xg[cho + (p << 8)];
      a_nxt0 = *(const short8*)(ap + cha);
      a_nxt1 = *(const short8*)(ap + cha + 32);
    }
    #pragma unroll
    for (int i = 0; i < 8; ++i)
      ssum += bf2f((unsigned short)a_cur0[i]) + bf2f((unsigned short)a_cur1[i]);
    #pragma unroll
    for (int ns = 0; ns < 64; ns += 32) {
      const short8 af = ns == 0 ? a_cur0 : a_cur1;
      #pragma unroll
      for (int ct = 0; ct < 4; ++ct) {
        const int row = (ct << 4) + lr;
        const unsigned long long* bp = (const unsigned long long*)
            &xs[cur][row * XRS + (ns >> 1) + (lg << 2)];
        union { unsigned long long q[2]; short8 s; } u;
        u.q[0] = bp[0];
        u.q[1] = bp[1];
        acc[ct] = __builtin_amdgcn_mfma_f32_16x16x32_bf16(af, u.s, acc[ct], 0, 0, 0);
      }
    }
    if (it < 15) {
      #pragma unroll
      for (int p = 0; p < 8; ++p) {
        const int f = (p << 8) + tid;
        xs[cur ^ 1][(f >> 5) * XRS + (f & 31)] = xr[p];
      }
      a_cur0 = a_nxt0;
      a_cur1 = a_nxt1;
    }
    lgkm_barrier();
  }

  // a_sum reduce over lg groups; lane lr holds a_sum for k=16w+lr
  ssum += __shfl_xor(ssum, 16);
  ssum += __shfl_xor(ssum, 32);

  float lsum = 0.f;
  #pragma unroll
  for (int j = 0; j < 4; ++j) {
    const float asum_e = __shfl(ssum, (lg << 2) + j);   // a_sum[k=16w+lg*4+j]
    #pragma unroll
    for (int ct = 0; ct < 4; ++ct) {
      int k = (w << 4) + (lg << 2) + j;
      int c = c0 + (ct << 4) + lr;
      float v = acc[ct][j] - asum_e * cc[k * CDIM + c];
      out[((size_t)b << 15) + (k << 9) + c] = v;
      lsum += v * v;
    }
  }
  lsum += __shfl_xor(lsum, 1);  lsum += __shfl_xor(lsum, 2);
  lsum += __shfl_xor(lsum, 4);  lsum += __shfl_xor(lsum, 8);
  lsum += __shfl_xor(lsum, 16); lsum += __shfl_xor(lsum, 32);
  if (l == 0) red[w] = lsum;
  __syncthreads();
  if (tid == 0) atomicAdd(&sumsq[b], red[0] + red[1] + red[2] + red[3]);
}

// ---------------- K3: l2 normalize per batch ----------------
__global__ __launch_bounds__(256) void k3_norm(float* __restrict__ out,
                                               const float* __restrict__ sumsq) {
  int idx = blockIdx.x * 256 + threadIdx.x;   // grid exact: 2048*256 = 2M/4
  int b = idx >> 13;                          // 8192 float4 per batch
  float s = sumsq[b];
  float scale = 1.0f / sqrtf(fmaxf(s, 1e-12f));
  f32x4* io = (f32x4*)out;
  f32x4 v = io[idx];
  v[0] *= scale; v[1] *= scale; v[2] *= scale; v[3] *= scale;
  io[idx] = v;
}

extern "C" void kernel_launch(void* const* d_in, const int* in_sizes, int n_in,
                              void* d_out, int out_size, void* d_ws, size_t ws_size,
                              hipStream_t stream) {
  const float* x  = (const float*)d_in[0];
  const float* cc = (const float*)d_in[1];
  float* out = (float*)d_out;
  char* ws = (char*)d_ws;
  // ws: [a_t bf16 8MiB][ccb 64KiB][sumsq 256B] ... [xT 64MiB @16MiB]
  unsigned short* a_t = (unsigned short*)ws;
  unsigned int* a_t32 = (unsigned int*)ws;
  unsigned short* ccb = (unsigned short*)(ws + (8u << 20));
  float* sumsq = (float*)(ws + (8u << 20) + (64u << 10));
  unsigned int* xT32 = (unsigned int*)(ws + (16u << 20));

  (void)hipMemsetAsync(sumsq, 0, NB * 4, stream);
  k0_cvt<<<dim3((KK * CDIM) / 256), 256, 0, stream>>>(cc, ccb);
  k1_assign<<<dim3(8, NB), 256, 0, stream>>>(x, ccb, a_t32, xT32);
  k2_agg<<<dim3(8, NB), 256, 0, stream>>>(a_t, xT32, cc, out, sumsq);
  k3_norm<<<dim3(2048), 256, 0, stream>>>(out, sumsq);
}